// Round 2
// baseline (587.165 us; speedup 1.0000x reference)
//
#include <hip/hip_runtime.h>

#define BATCH   262144
#define IN_DIM  28
#define HID     128
#define LAT     64
#define NCODES  512

typedef short v8s __attribute__((ext_vector_type(8)));
typedef float v4f __attribute__((ext_vector_type(4)));

__device__ __forceinline__ unsigned short f2bf(float f) {
  unsigned u = __float_as_uint(f);
  u += 0x7fffu + ((u >> 16) & 1u);   // round-to-nearest-even
  return (unsigned short)(u >> 16);
}

// ---------------- prep: bf16 fragment-layout weights into ws ----------------
__global__ __launch_bounds__(256) void vq_prep(
    const float* __restrict__ ew1, const float* __restrict__ ew2,
    const float* __restrict__ cb,  const float* __restrict__ dw1,
    const float* __restrict__ dw2,
    unsigned short* __restrict__ w1t, unsigned short* __restrict__ w2t,
    unsigned short* __restrict__ cbt, unsigned short* __restrict__ dw1t,
    unsigned short* __restrict__ dw2t, float* __restrict__ e2,
    float* __restrict__ sums) {
  int i = blockIdx.x * 256 + threadIdx.x;
  if (i < 4096) {                       // w1t [128][32]: enc_w1^T, k>=28 zero
    int n = i >> 5, k = i & 31;
    w1t[i] = (k < IN_DIM) ? f2bf(ew1[k * HID + n]) : (unsigned short)0;
  } else if (i < 12288) {               // w2t [64][128]: enc_w2^T
    int j = i - 4096; int n = j >> 7, k = j & 127;
    w2t[j] = f2bf(ew2[k * LAT + n]);
  } else if (i < 45056) {               // cbt [512][64]
    int j = i - 12288;
    cbt[j] = f2bf(cb[j]);
  } else if (i < 53248) {               // dw1t [128][64]: dec_w1^T
    int j = i - 45056; int n = j >> 6, k = j & 63;
    dw1t[j] = f2bf(dw1[k * HID + n]);
  } else if (i < 57344) {               // dw2t [32][128]: dec_w2^T, n>=28 zero
    int j = i - 53248; int n = j >> 7, k = j & 127;
    dw2t[j] = (n < IN_DIM) ? f2bf(dw2[k * IN_DIM + n]) : (unsigned short)0;
  } else if (i < 57856) {               // e2
    int c = i - 57344;
    float s = 0.f;
    for (int d = 0; d < LAT; ++d) { float v = cb[c * LAT + d]; s += v * v; }
    e2[c] = s;
  } else if (i == 57856) {
    sums[0] = 0.f; sums[1] = 0.f;
  }
}

// ---------------- fused main kernel ----------------
// Per-wave LDS buffer (2176 shorts) reused across stages: H (16x128, stride
// 136) -> Z (16x64, stride 72) -> HD (16x128, stride 136). No __syncthreads:
// each wave touches only its own region; every reuse has a true data
// dependency (reads precede dependent writes in dataflow), so in-order DS
// execution per wave guarantees correctness.
__global__ __launch_bounds__(256) void vq_main(
    const float* __restrict__ x,
    const float* __restrict__ b1, const float* __restrict__ b2,
    const float* __restrict__ cbf, const float* __restrict__ db1,
    const float* __restrict__ db2,
    const unsigned short* __restrict__ w1t, const unsigned short* __restrict__ w2t,
    const unsigned short* __restrict__ cbt, const unsigned short* __restrict__ dw1t,
    const unsigned short* __restrict__ dw2t, const float* __restrict__ e2,
    float* __restrict__ out, float* __restrict__ sums) {

  __shared__ __align__(16) unsigned short buf[4][16 * 136];

  const int tid  = threadIdx.x;
  const int wave = tid >> 6;
  const int lane = tid & 63;
  const int quad = lane >> 4;
  const int lm   = lane & 15;
  const int r0   = blockIdx.x * 64 + wave * 16;   // this wave's 16 rows

  unsigned short* W = &buf[wave][0];

  const v4f zero4 = {0.f, 0.f, 0.f, 0.f};

  // ---- stage 1: H = relu(X @ W1 + b1), M=16 K=32(28) N=128 ----
  v8s a1;
  {
    const float* xp = x + (size_t)(r0 + lm) * IN_DIM + quad * 8;
    float4 v0 = *(const float4*)xp;
    float4 v1;
    if (quad == 3) { v1.x = 0.f; v1.y = 0.f; v1.z = 0.f; v1.w = 0.f; }
    else           { v1 = *(const float4*)(xp + 4); }
    a1[0] = (short)f2bf(v0.x); a1[1] = (short)f2bf(v0.y);
    a1[2] = (short)f2bf(v0.z); a1[3] = (short)f2bf(v0.w);
    a1[4] = (short)f2bf(v1.x); a1[5] = (short)f2bf(v1.y);
    a1[6] = (short)f2bf(v1.z); a1[7] = (short)f2bf(v1.w);
  }
  {
    v4f acc[8];
#pragma unroll
    for (int nt = 0; nt < 8; ++nt) {
      v8s b = *(const v8s*)(w1t + (nt * 16 + lm) * 32 + quad * 8);
      acc[nt] = __builtin_amdgcn_mfma_f32_16x16x32_bf16(a1, b, zero4, 0, 0, 0);
    }
#pragma unroll
    for (int nt = 0; nt < 8; ++nt) {
      float bias = b1[nt * 16 + lm];
#pragma unroll
      for (int r = 0; r < 4; ++r) {
        float h = fmaxf(acc[nt][r] + bias, 0.f);
        W[(quad * 4 + r) * 136 + nt * 16 + lm] = f2bf(h);
      }
    }
  }

  // ---- stage 2: Z = H @ W2 + b2, M=16 K=128 N=64 (z fp32 in regs) ----
  v4f accz[4];
  {
    v8s ha[4];
#pragma unroll
    for (int ks = 0; ks < 4; ++ks)
      ha[ks] = *(const v8s*)&W[lm * 136 + ks * 32 + quad * 8];
#pragma unroll
    for (int nt = 0; nt < 4; ++nt) accz[nt] = zero4;
#pragma unroll
    for (int nt = 0; nt < 4; ++nt) {
#pragma unroll
      for (int ks = 0; ks < 4; ++ks) {
        v8s b = *(const v8s*)(w2t + (nt * 16 + lm) * 128 + ks * 32 + quad * 8);
        accz[nt] = __builtin_amdgcn_mfma_f32_16x16x32_bf16(ha[ks], b, accz[nt], 0, 0, 0);
      }
    }
    // write z (bf16) into the same wave buffer, stride 72
#pragma unroll
    for (int nt = 0; nt < 4; ++nt) {
      float bias = b2[nt * 16 + lm];
#pragma unroll
      for (int r = 0; r < 4; ++r) {
        accz[nt][r] += bias;
        W[(quad * 4 + r) * 72 + nt * 16 + lm] = f2bf(accz[nt][r]);
      }
    }
  }

  // ---- stage 3: distances + argmin, two independent chains ----
  float bd0[4], bd1[4]; int bc0[4], bc1[4];
#pragma unroll
  for (int r = 0; r < 4; ++r) {
    bd0[r] = 3.4e38f; bc0[r] = 0x7fffffff;
    bd1[r] = 3.4e38f; bc1[r] = 0x7fffffff;
  }
  {
    v8s za0 = *(const v8s*)&W[lm * 72 + quad * 8];
    v8s za1 = *(const v8s*)&W[lm * 72 + 32 + quad * 8];
#pragma unroll 4
    for (int nt = 0; nt < 16; ++nt) {
      int c0 = nt * 16 + lm;
      int c1 = c0 + 256;
      v8s p0 = *(const v8s*)(cbt + c0 * 64 + quad * 8);
      v8s p1 = *(const v8s*)(cbt + c0 * 64 + 32 + quad * 8);
      v8s q0 = *(const v8s*)(cbt + c1 * 64 + quad * 8);
      v8s q1 = *(const v8s*)(cbt + c1 * 64 + 32 + quad * 8);
      v4f accA = __builtin_amdgcn_mfma_f32_16x16x32_bf16(za0, p0, zero4, 0, 0, 0);
      accA = __builtin_amdgcn_mfma_f32_16x16x32_bf16(za1, p1, accA, 0, 0, 0);
      v4f accB = __builtin_amdgcn_mfma_f32_16x16x32_bf16(za0, q0, zero4, 0, 0, 0);
      accB = __builtin_amdgcn_mfma_f32_16x16x32_bf16(za1, q1, accB, 0, 0, 0);
      float eA = e2[c0], eB = e2[c1];
#pragma unroll
      for (int r = 0; r < 4; ++r) {
        float dA = eA - 2.f * accA[r];
        float dB = eB - 2.f * accB[r];
        if (dA < bd0[r]) { bd0[r] = dA; bc0[r] = c0; }
        if (dB < bd1[r]) { bd1[r] = dB; bc1[r] = c1; }
      }
    }
  }
  // merge chains (strict <: every c1 > every c0 within a lane, so ties keep c0)
  float bestd[4]; int bestc[4];
#pragma unroll
  for (int r = 0; r < 4; ++r) {
    bestd[r] = bd0[r]; bestc[r] = bc0[r];
    if (bd1[r] < bestd[r]) { bestd[r] = bd1[r]; bestc[r] = bc1[r]; }
  }
  // reduce argmin across the 16 lanes of each quad-group (rows m = quad*4+r)
#pragma unroll
  for (int off = 1; off < 16; off <<= 1) {
#pragma unroll
    for (int r = 0; r < 4; ++r) {
      float od = __shfl_xor(bestd[r], off, 64);
      int   oc = __shfl_xor(bestc[r], off, 64);
      if (od < bestd[r] || (od == bestd[r] && oc < bestc[r])) { bestd[r] = od; bestc[r] = oc; }
    }
  }

  // ---- vq loss partial: sum (z - q)^2, fp32 z and fp32 codebook ----
  float vqacc = 0.f;
#pragma unroll
  for (int r = 0; r < 4; ++r) {
    const float* qrow = cbf + (size_t)bestc[r] * LAT;
#pragma unroll
    for (int nt = 0; nt < 4; ++nt) {
      float d = accz[nt][r] - qrow[nt * 16 + lm];
      vqacc += d * d;
    }
  }

  // broadcast idx[m] so every lane knows the code for row m = lm
  int i0 = __shfl(bestc[0], (lm >> 2) << 4, 64);
  int i1 = __shfl(bestc[1], (lm >> 2) << 4, 64);
  int i2 = __shfl(bestc[2], (lm >> 2) << 4, 64);
  int i3 = __shfl(bestc[3], (lm >> 2) << 4, 64);
  int sel = lm & 3;
  int idxv = sel == 0 ? i0 : sel == 1 ? i1 : sel == 2 ? i2 : i3;

  // ---- stage 5: HD = relu(Q @ DW1 + db1), M=16 K=64 N=128 ----
  {
    v8s qa0 = *(const v8s*)(cbt + (size_t)idxv * 64 + quad * 8);
    v8s qa1 = *(const v8s*)(cbt + (size_t)idxv * 64 + 32 + quad * 8);
    v4f acc[8];
#pragma unroll
    for (int nt = 0; nt < 8; ++nt) acc[nt] = zero4;
#pragma unroll
    for (int nt = 0; nt < 8; ++nt) {
      v8s b0 = *(const v8s*)(dw1t + (nt * 16 + lm) * 64 + quad * 8);
      v8s b1v = *(const v8s*)(dw1t + (nt * 16 + lm) * 64 + 32 + quad * 8);
      acc[nt] = __builtin_amdgcn_mfma_f32_16x16x32_bf16(qa0, b0, acc[nt], 0, 0, 0);
      acc[nt] = __builtin_amdgcn_mfma_f32_16x16x32_bf16(qa1, b1v, acc[nt], 0, 0, 0);
    }
#pragma unroll
    for (int nt = 0; nt < 8; ++nt) {
      float bias = db1[nt * 16 + lm];
#pragma unroll
      for (int r = 0; r < 4; ++r) {
        float h = fmaxf(acc[nt][r] + bias, 0.f);
        W[(quad * 4 + r) * 136 + nt * 16 + lm] = f2bf(h);
      }
    }
  }

  // ---- stage 6: R = HD @ DW2 + db2, M=16 K=128 N=32(28); store + recon loss ----
  float racc = 0.f;
  {
    v8s hd[4];
#pragma unroll
    for (int ks = 0; ks < 4; ++ks)
      hd[ks] = *(const v8s*)&W[lm * 136 + ks * 32 + quad * 8];
    v4f acc[2];
#pragma unroll
    for (int nt = 0; nt < 2; ++nt) acc[nt] = zero4;
#pragma unroll
    for (int nt = 0; nt < 2; ++nt) {
#pragma unroll
      for (int ks = 0; ks < 4; ++ks) {
        v8s b = *(const v8s*)(dw2t + (nt * 16 + lm) * 128 + ks * 32 + quad * 8);
        acc[nt] = __builtin_amdgcn_mfma_f32_16x16x32_bf16(hd[ks], b, acc[nt], 0, 0, 0);
      }
    }
#pragma unroll
    for (int nt = 0; nt < 2; ++nt) {
      int n = nt * 16 + lm;
      bool valid = (n < IN_DIM);
      float bias = valid ? db2[n] : 0.f;
#pragma unroll
      for (int r = 0; r < 4; ++r) {
        int m = quad * 4 + r;
        float rec = acc[nt][r] + bias;
        if (valid) {
          size_t o = (size_t)(r0 + m) * IN_DIM + n;
          out[o] = rec;
          float dv = rec - x[o];
          racc += dv * dv;
        }
      }
    }
  }

  // ---- loss reduction: 64-lane butterfly then one atomic per wave ----
#pragma unroll
  for (int off = 1; off < 64; off <<= 1) {
    racc  += __shfl_xor(racc, off, 64);
    vqacc += __shfl_xor(vqacc, off, 64);
  }
  if (lane == 0) {
    atomicAdd(&sums[0], racc);
    atomicAdd(&sums[1], vqacc);
  }
}

// ---------------- finalize scalars ----------------
__global__ void vq_fin(const float* __restrict__ sums, float* __restrict__ out) {
  if (threadIdx.x == 0) {
    out[7340032] = sums[0] * (1.0f / 7340032.0f);          // recon_loss = S / (B*28)
    out[7340033] = sums[1] * (1.25f / 16777216.0f);        // vq_loss = 1.25 * S / (B*64)
  }
}

extern "C" void kernel_launch(void* const* d_in, const int* in_sizes, int n_in,
                              void* d_out, int out_size, void* d_ws, size_t ws_size,
                              hipStream_t stream) {
  const float* x   = (const float*)d_in[0];
  const float* ew1 = (const float*)d_in[1];
  const float* eb1 = (const float*)d_in[2];
  const float* ew2 = (const float*)d_in[3];
  const float* eb2 = (const float*)d_in[4];
  const float* cb  = (const float*)d_in[5];
  const float* dw1 = (const float*)d_in[6];
  const float* db1 = (const float*)d_in[7];
  const float* dw2 = (const float*)d_in[8];
  const float* db2 = (const float*)d_in[9];

  char* ws = (char*)d_ws;
  unsigned short* w1t  = (unsigned short*)(ws + 0);        //  8192 B
  unsigned short* w2t  = (unsigned short*)(ws + 8192);     // 16384 B
  unsigned short* cbt  = (unsigned short*)(ws + 24576);    // 65536 B
  unsigned short* dw1t = (unsigned short*)(ws + 90112);    // 16384 B
  unsigned short* dw2t = (unsigned short*)(ws + 106496);   //  8192 B
  float* e2   = (float*)(ws + 114688);                     //  2048 B
  float* sums = (float*)(ws + 116736);                     //     8 B

  float* out = (float*)d_out;

  vq_prep<<<227, 256, 0, stream>>>(ew1, ew2, cb, dw1, dw2,
                                   w1t, w2t, cbt, dw1t, dw2t, e2, sums);
  vq_main<<<BATCH / 64, 256, 0, stream>>>(x, eb1, eb2, cb, db1, db2,
                                          w1t, w2t, cbt, dw1t, dw2t, e2, out, sums);
  vq_fin<<<1, 64, 0, stream>>>(sums, out);
}

// Round 3
// 333.680 us; speedup vs baseline: 1.7597x; 1.7597x over previous
//
#include <hip/hip_runtime.h>

#define BATCH   262144
#define IN_DIM  28
#define HID     128
#define LAT     64
#define NCODES  512
#define NBLK    (BATCH / 64)

typedef short v8s __attribute__((ext_vector_type(8)));
typedef float v4f __attribute__((ext_vector_type(4)));

__device__ __forceinline__ unsigned short f2bf(float f) {
  unsigned u = __float_as_uint(f);
  u += 0x7fffu + ((u >> 16) & 1u);   // round-to-nearest-even
  return (unsigned short)(u >> 16);
}

// ---------------- prep: bf16 fragment-layout weights into ws ----------------
__global__ __launch_bounds__(256) void vq_prep(
    const float* __restrict__ ew1, const float* __restrict__ ew2,
    const float* __restrict__ cb,  const float* __restrict__ dw1,
    const float* __restrict__ dw2,
    unsigned short* __restrict__ w1t, unsigned short* __restrict__ w2t,
    unsigned short* __restrict__ cbt, unsigned short* __restrict__ dw1t,
    unsigned short* __restrict__ dw2t, float* __restrict__ e2) {
  int i = blockIdx.x * 256 + threadIdx.x;
  if (i < 4096) {                       // w1t [128][32]: enc_w1^T, k>=28 zero
    int n = i >> 5, k = i & 31;
    w1t[i] = (k < IN_DIM) ? f2bf(ew1[k * HID + n]) : (unsigned short)0;
  } else if (i < 12288) {               // w2t [64][128]: enc_w2^T
    int j = i - 4096; int n = j >> 7, k = j & 127;
    w2t[j] = f2bf(ew2[k * LAT + n]);
  } else if (i < 45056) {               // cbt [512][64]
    int j = i - 12288;
    cbt[j] = f2bf(cb[j]);
  } else if (i < 53248) {               // dw1t [128][64]: dec_w1^T
    int j = i - 45056; int n = j >> 6, k = j & 63;
    dw1t[j] = f2bf(dw1[k * HID + n]);
  } else if (i < 57344) {               // dw2t [32][128]: dec_w2^T, n>=28 zero
    int j = i - 53248; int n = j >> 7, k = j & 127;
    dw2t[j] = (n < IN_DIM) ? f2bf(dw2[k * IN_DIM + n]) : (unsigned short)0;
  } else if (i < 57856) {               // e2
    int c = i - 57344;
    float s = 0.f;
    for (int d = 0; d < LAT; ++d) { float v = cb[c * LAT + d]; s += v * v; }
    e2[c] = s;
  }
}

// ---------------- fused main kernel ----------------
// Per-wave LDS buffer (2176 shorts) reused across stages: H (16x128, stride
// 136) -> Z (16x64, stride 72) -> HD (16x128, stride 136). No mid-kernel
// __syncthreads: each wave touches only its own region. Losses: per-wave
// butterfly -> LDS -> one per-block partial pair in ws (NO global atomics —
// round-2 evidence: 32768 same-address atomicAdds serialized the grid at
// ~37 cyc each ≈ the entire 505 us).
__global__ __launch_bounds__(256) void vq_main(
    const float* __restrict__ x,
    const float* __restrict__ b1, const float* __restrict__ b2,
    const float* __restrict__ cbf, const float* __restrict__ db1,
    const float* __restrict__ db2,
    const unsigned short* __restrict__ w1t, const unsigned short* __restrict__ w2t,
    const unsigned short* __restrict__ cbt, const unsigned short* __restrict__ dw1t,
    const unsigned short* __restrict__ dw2t, const float* __restrict__ e2,
    float* __restrict__ out, float* __restrict__ partials) {

  __shared__ __align__(16) unsigned short buf[4][16 * 136];
  __shared__ float wsum[4][2];

  const int tid  = threadIdx.x;
  const int wave = tid >> 6;
  const int lane = tid & 63;
  const int quad = lane >> 4;
  const int lm   = lane & 15;
  const int r0   = blockIdx.x * 64 + wave * 16;   // this wave's 16 rows

  unsigned short* W = &buf[wave][0];

  const v4f zero4 = {0.f, 0.f, 0.f, 0.f};

  // ---- stage 1: H = relu(X @ W1 + b1), M=16 K=32(28) N=128 ----
  v8s a1;
  {
    const float* xp = x + (size_t)(r0 + lm) * IN_DIM + quad * 8;
    float4 v0 = *(const float4*)xp;
    float4 v1;
    if (quad == 3) { v1.x = 0.f; v1.y = 0.f; v1.z = 0.f; v1.w = 0.f; }
    else           { v1 = *(const float4*)(xp + 4); }
    a1[0] = (short)f2bf(v0.x); a1[1] = (short)f2bf(v0.y);
    a1[2] = (short)f2bf(v0.z); a1[3] = (short)f2bf(v0.w);
    a1[4] = (short)f2bf(v1.x); a1[5] = (short)f2bf(v1.y);
    a1[6] = (short)f2bf(v1.z); a1[7] = (short)f2bf(v1.w);
  }
  {
    v4f acc[8];
#pragma unroll
    for (int nt = 0; nt < 8; ++nt) {
      v8s b = *(const v8s*)(w1t + (nt * 16 + lm) * 32 + quad * 8);
      acc[nt] = __builtin_amdgcn_mfma_f32_16x16x32_bf16(a1, b, zero4, 0, 0, 0);
    }
#pragma unroll
    for (int nt = 0; nt < 8; ++nt) {
      float bias = b1[nt * 16 + lm];
#pragma unroll
      for (int r = 0; r < 4; ++r) {
        float h = fmaxf(acc[nt][r] + bias, 0.f);
        W[(quad * 4 + r) * 136 + nt * 16 + lm] = f2bf(h);
      }
    }
  }

  // ---- stage 2: Z = H @ W2 + b2, M=16 K=128 N=64 (z fp32 in regs) ----
  v4f accz[4];
  {
    v8s ha[4];
#pragma unroll
    for (int ks = 0; ks < 4; ++ks)
      ha[ks] = *(const v8s*)&W[lm * 136 + ks * 32 + quad * 8];
#pragma unroll
    for (int nt = 0; nt < 4; ++nt) accz[nt] = zero4;
#pragma unroll
    for (int nt = 0; nt < 4; ++nt) {
#pragma unroll
      for (int ks = 0; ks < 4; ++ks) {
        v8s b = *(const v8s*)(w2t + (nt * 16 + lm) * 128 + ks * 32 + quad * 8);
        accz[nt] = __builtin_amdgcn_mfma_f32_16x16x32_bf16(ha[ks], b, accz[nt], 0, 0, 0);
      }
    }
#pragma unroll
    for (int nt = 0; nt < 4; ++nt) {
      float bias = b2[nt * 16 + lm];
#pragma unroll
      for (int r = 0; r < 4; ++r) {
        accz[nt][r] += bias;
        W[(quad * 4 + r) * 72 + nt * 16 + lm] = f2bf(accz[nt][r]);
      }
    }
  }

  // ---- stage 3: distances + argmin, two independent chains ----
  float bd0[4], bd1[4]; int bc0[4], bc1[4];
#pragma unroll
  for (int r = 0; r < 4; ++r) {
    bd0[r] = 3.4e38f; bc0[r] = 0x7fffffff;
    bd1[r] = 3.4e38f; bc1[r] = 0x7fffffff;
  }
  {
    v8s za0 = *(const v8s*)&W[lm * 72 + quad * 8];
    v8s za1 = *(const v8s*)&W[lm * 72 + 32 + quad * 8];
#pragma unroll 4
    for (int nt = 0; nt < 16; ++nt) {
      int c0 = nt * 16 + lm;
      int c1 = c0 + 256;
      v8s p0 = *(const v8s*)(cbt + c0 * 64 + quad * 8);
      v8s p1 = *(const v8s*)(cbt + c0 * 64 + 32 + quad * 8);
      v8s q0 = *(const v8s*)(cbt + c1 * 64 + quad * 8);
      v8s q1 = *(const v8s*)(cbt + c1 * 64 + 32 + quad * 8);
      v4f accA = __builtin_amdgcn_mfma_f32_16x16x32_bf16(za0, p0, zero4, 0, 0, 0);
      accA = __builtin_amdgcn_mfma_f32_16x16x32_bf16(za1, p1, accA, 0, 0, 0);
      v4f accB = __builtin_amdgcn_mfma_f32_16x16x32_bf16(za0, q0, zero4, 0, 0, 0);
      accB = __builtin_amdgcn_mfma_f32_16x16x32_bf16(za1, q1, accB, 0, 0, 0);
      float eA = e2[c0], eB = e2[c1];
#pragma unroll
      for (int r = 0; r < 4; ++r) {
        float dA = eA - 2.f * accA[r];
        float dB = eB - 2.f * accB[r];
        if (dA < bd0[r]) { bd0[r] = dA; bc0[r] = c0; }
        if (dB < bd1[r]) { bd1[r] = dB; bc1[r] = c1; }
      }
    }
  }
  float bestd[4]; int bestc[4];
#pragma unroll
  for (int r = 0; r < 4; ++r) {
    bestd[r] = bd0[r]; bestc[r] = bc0[r];
    if (bd1[r] < bestd[r]) { bestd[r] = bd1[r]; bestc[r] = bc1[r]; }
  }
  // reduce argmin across the 16 lanes of each quad-group (rows m = quad*4+r)
#pragma unroll
  for (int off = 1; off < 16; off <<= 1) {
#pragma unroll
    for (int r = 0; r < 4; ++r) {
      float od = __shfl_xor(bestd[r], off, 64);
      int   oc = __shfl_xor(bestc[r], off, 64);
      if (od < bestd[r] || (od == bestd[r] && oc < bestc[r])) { bestd[r] = od; bestc[r] = oc; }
    }
  }

  // ---- vq loss partial: sum (z - q)^2, fp32 z and fp32 codebook ----
  float vqacc = 0.f;
#pragma unroll
  for (int r = 0; r < 4; ++r) {
    const float* qrow = cbf + (size_t)bestc[r] * LAT;
#pragma unroll
    for (int nt = 0; nt < 4; ++nt) {
      float d = accz[nt][r] - qrow[nt * 16 + lm];
      vqacc += d * d;
    }
  }

  // broadcast idx[m] so every lane knows the code for row m = lm
  int i0 = __shfl(bestc[0], (lm >> 2) << 4, 64);
  int i1 = __shfl(bestc[1], (lm >> 2) << 4, 64);
  int i2 = __shfl(bestc[2], (lm >> 2) << 4, 64);
  int i3 = __shfl(bestc[3], (lm >> 2) << 4, 64);
  int sel = lm & 3;
  int idxv = sel == 0 ? i0 : sel == 1 ? i1 : sel == 2 ? i2 : i3;

  // ---- stage 5: HD = relu(Q @ DW1 + db1), M=16 K=64 N=128 ----
  {
    v8s qa0 = *(const v8s*)(cbt + (size_t)idxv * 64 + quad * 8);
    v8s qa1 = *(const v8s*)(cbt + (size_t)idxv * 64 + 32 + quad * 8);
    v4f acc[8];
#pragma unroll
    for (int nt = 0; nt < 8; ++nt) acc[nt] = zero4;
#pragma unroll
    for (int nt = 0; nt < 8; ++nt) {
      v8s b0 = *(const v8s*)(dw1t + (nt * 16 + lm) * 64 + quad * 8);
      v8s b1v = *(const v8s*)(dw1t + (nt * 16 + lm) * 64 + 32 + quad * 8);
      acc[nt] = __builtin_amdgcn_mfma_f32_16x16x32_bf16(qa0, b0, acc[nt], 0, 0, 0);
      acc[nt] = __builtin_amdgcn_mfma_f32_16x16x32_bf16(qa1, b1v, acc[nt], 0, 0, 0);
    }
#pragma unroll
    for (int nt = 0; nt < 8; ++nt) {
      float bias = db1[nt * 16 + lm];
#pragma unroll
      for (int r = 0; r < 4; ++r) {
        float h = fmaxf(acc[nt][r] + bias, 0.f);
        W[(quad * 4 + r) * 136 + nt * 16 + lm] = f2bf(h);
      }
    }
  }

  // ---- stage 6: R = HD @ DW2 + db2, M=16 K=128 N=32(28); store + recon loss ----
  float racc = 0.f;
  {
    v8s hd[4];
#pragma unroll
    for (int ks = 0; ks < 4; ++ks)
      hd[ks] = *(const v8s*)&W[lm * 136 + ks * 32 + quad * 8];
    v4f acc[2];
#pragma unroll
    for (int nt = 0; nt < 2; ++nt) acc[nt] = zero4;
#pragma unroll
    for (int nt = 0; nt < 2; ++nt) {
#pragma unroll
      for (int ks = 0; ks < 4; ++ks) {
        v8s b = *(const v8s*)(dw2t + (nt * 16 + lm) * 128 + ks * 32 + quad * 8);
        acc[nt] = __builtin_amdgcn_mfma_f32_16x16x32_bf16(hd[ks], b, acc[nt], 0, 0, 0);
      }
    }
#pragma unroll
    for (int nt = 0; nt < 2; ++nt) {
      int n = nt * 16 + lm;
      bool valid = (n < IN_DIM);
      float bias = valid ? db2[n] : 0.f;
#pragma unroll
      for (int r = 0; r < 4; ++r) {
        int m = quad * 4 + r;
        float rec = acc[nt][r] + bias;
        if (valid) {
          size_t o = (size_t)(r0 + m) * IN_DIM + n;
          out[o] = rec;
          float dv = rec - x[o];
          racc += dv * dv;
        }
      }
    }
  }

  // ---- loss reduction: butterfly -> LDS -> ONE per-block partial (no atomics) ----
#pragma unroll
  for (int off = 1; off < 64; off <<= 1) {
    racc  += __shfl_xor(racc, off, 64);
    vqacc += __shfl_xor(vqacc, off, 64);
  }
  if (lane == 0) { wsum[wave][0] = racc; wsum[wave][1] = vqacc; }
  __syncthreads();
  if (tid == 0) {
    partials[(size_t)blockIdx.x * 2]     = wsum[0][0] + wsum[1][0] + wsum[2][0] + wsum[3][0];
    partials[(size_t)blockIdx.x * 2 + 1] = wsum[0][1] + wsum[1][1] + wsum[2][1] + wsum[3][1];
  }
}

// ---------------- finalize: reduce per-block partials, write scalars ----------------
__global__ __launch_bounds__(256) void vq_fin(const float* __restrict__ partials,
                                              float* __restrict__ out) {
  float r = 0.f, v = 0.f;
  for (int i = threadIdx.x; i < NBLK; i += 256) {
    r += partials[2 * i];
    v += partials[2 * i + 1];
  }
#pragma unroll
  for (int off = 1; off < 64; off <<= 1) {
    r += __shfl_xor(r, off, 64);
    v += __shfl_xor(v, off, 64);
  }
  __shared__ float s[4][2];
  int w = threadIdx.x >> 6;
  if ((threadIdx.x & 63) == 0) { s[w][0] = r; s[w][1] = v; }
  __syncthreads();
  if (threadIdx.x == 0) {
    float R = s[0][0] + s[1][0] + s[2][0] + s[3][0];
    float V = s[0][1] + s[1][1] + s[2][1] + s[3][1];
    out[7340032] = R * (1.0f / 7340032.0f);          // recon_loss = S / (B*28)
    out[7340033] = V * (1.25f / 16777216.0f);        // vq_loss = 1.25 * S / (B*64)
  }
}

extern "C" void kernel_launch(void* const* d_in, const int* in_sizes, int n_in,
                              void* d_out, int out_size, void* d_ws, size_t ws_size,
                              hipStream_t stream) {
  const float* x   = (const float*)d_in[0];
  const float* ew1 = (const float*)d_in[1];
  const float* eb1 = (const float*)d_in[2];
  const float* ew2 = (const float*)d_in[3];
  const float* eb2 = (const float*)d_in[4];
  const float* cb  = (const float*)d_in[5];
  const float* dw1 = (const float*)d_in[6];
  const float* db1 = (const float*)d_in[7];
  const float* dw2 = (const float*)d_in[8];
  const float* db2 = (const float*)d_in[9];

  char* ws = (char*)d_ws;
  unsigned short* w1t  = (unsigned short*)(ws + 0);        //  8192 B
  unsigned short* w2t  = (unsigned short*)(ws + 8192);     // 16384 B
  unsigned short* cbt  = (unsigned short*)(ws + 24576);    // 65536 B
  unsigned short* dw1t = (unsigned short*)(ws + 90112);    // 16384 B
  unsigned short* dw2t = (unsigned short*)(ws + 106496);   //  8192 B
  float* e2       = (float*)(ws + 114688);                 //  2048 B
  float* partials = (float*)(ws + 116736);                 // 32768 B (4096*2 f32)

  float* out = (float*)d_out;

  vq_prep<<<227, 256, 0, stream>>>(ew1, ew2, cb, dw1, dw2,
                                   w1t, w2t, cbt, dw1t, dw2t, e2);
  vq_main<<<NBLK, 256, 0, stream>>>(x, eb1, eb2, cb, db1, db2,
                                    w1t, w2t, cbt, dw1t, dw2t, e2, out, partials);
  vq_fin<<<1, 256, 0, stream>>>(partials, out);
}